// Round 13
// baseline (142.042 us; speedup 1.0000x reference)
//
#include <hip/hip_runtime.h>
#include <hip/hip_bf16.h>
#include <math.h>

#define BATCH 2
#define NPTS 4096
#define DIM 128
#define HID 12
#define KNN 16
#define NSLOT 24   // sorted candidate list (top-24 by f32-lex, refined by f64)
#define BCAP 192   // append buffer capacity per wave
#define BCT 64     // compact threshold (checked before each 128-pt tile)
#define PTQ 4      // queries per pt_wave block (grid-stride)

// prep blocks first (stragglers start early), knn after
#define FOLD_BLOCKS 128
#define M1_BLOCKS 32
#define PRE_BLOCKS (FOLD_BLOCKS + M1_BLOCKS + 4)  // +pw2b +2*aw2b +wv = 164
#define KNN_BLOCKS (BATCH * NPTS / 2)             // 4096 (2 queries/block, 2 waves each)

typedef __attribute__((ext_vector_type(8))) short short8;
typedef __attribute__((ext_vector_type(4))) float f32x4;

// f32 -> bf16 round-to-nearest-even (finite values only)
__device__ __forceinline__ short f2b(float f) {
  unsigned u = __float_as_uint(f);
  unsigned r = (u + 0x7fffu + ((u >> 16) & 1u)) >> 16;
  return (short)r;
}
__device__ __forceinline__ float b2f(short h) {
  return __uint_as_float(((unsigned)(unsigned short)h) << 16);
}

// full-wave bitonic sort, ascending lexicographic by (value, index)
#define BITONIC64(v, vi)                                                     \
  {                                                                          \
    _Pragma("unroll") for (int k_ = 2; k_ <= 64; k_ <<= 1) {                 \
      _Pragma("unroll") for (int j_ = k_ >> 1; j_ >= 1; j_ >>= 1) {          \
        const float ov_ = __shfl_xor((v), j_);                               \
        const int oi_ = __shfl_xor((vi), j_);                                \
        const bool up_ = ((lane & k_) == 0);                                 \
        const bool lowpos_ = ((lane & j_) == 0);                             \
        const bool keep_min_ = (lowpos_ == up_);                             \
        const bool lt_ = (ov_ < (v)) || (ov_ == (v) && oi_ < (vi));          \
        const bool take_ = keep_min_ ? lt_ : !lt_;                           \
        if (take_) { (v) = ov_; (vi) = oi_; }                                \
      }                                                                      \
    }                                                                        \
  }

#define KNN_EVENTS(d2v, base, odd)                                        \
  {                                                                       \
    unsigned long long m_ = __ballot((d2v) < thr);                        \
    if (m_) {                                                             \
      const unsigned lt_ = __builtin_amdgcn_mbcnt_hi(                     \
          (unsigned)(m_ >> 32), __builtin_amdgcn_mbcnt_lo((unsigned)m_, 0u)); \
      if ((d2v) < thr) { bdl[bcount + lt_] = (d2v); bil[bcount + lt_] = (base) + 2 * lane + (odd); } \
      bcount += (int)__builtin_popcountll(m_);                            \
    }                                                                     \
  }

// ---------------------------------------------------------------------------
// KNN body: exact top-16 per query. TWO waves per query (each scans half the
// points = 16 tiles), own sorted top-24 via seed-bitonic + parallel-append +
// batch compaction; final LDS merge (bitonic-48) + exact f64 re-rank.
// Block = 256 threads = 2 queries.
// ---------------------------------------------------------------------------
__device__ void knn_body(int bid, const float* __restrict__ pos,
                         int* __restrict__ knn_out) {
  __shared__ float bd_s[4][BCAP];
  __shared__ int bi_s[4][BCAP];

  const int t = threadIdx.x;
  const int w = t >> 6;
  const int lane = t & 63;
  const int n = bid * 2 + (w >> 1);  // flattened (b,n), wave-uniform
  const int half = w & 1;
  const int b = n >> 12;
  const int qn = n & (NPTS - 1);
  const int base0 = half * (NPTS / 2);  // 0 or 2048

  float* bdl = &bd_s[w][0];
  int* bil = &bi_s[w][0];

  const float* pb = pos + b * NPTS * 3;
  const float qx = pb[qn * 3 + 0];
  const float qy = pb[qn * 3 + 1];
  const float qz = pb[qn * 3 + 2];

  const bool is_slot = (lane < NSLOT);
  float vald, thr;
  int validx;
  int bcount = 0;

  // ---- first tile of this half: seed via bitonic of even points ----
  {
    const float2* pp = (const float2*)(pb + base0 * 3 + lane * 6);
    const float2 u0 = pp[0], u1 = pp[1], u2 = pp[2];
    float dx = qx - u0.x, dy = qy - u0.y, dz = qz - u1.x;
    float v = fmaf(dx, dx, fmaf(dy, dy, dz * dz));
    int vi = base0 + lane * 2;
    dx = qx - u1.y; dy = qy - u2.x; dz = qz - u2.y;
    const float d2b = fmaf(dx, dx, fmaf(dy, dy, dz * dz));

    BITONIC64(v, vi)
    vald = is_slot ? v : __builtin_inff();
    validx = is_slot ? vi : 0x7fffffff;
    const float v15 = __shfl(v, 15);
    thr = v15 + v15 * 1e-5f;  // slack >> f32 rounding of d2

    KNN_EVENTS(d2b, base0, 1)
  }

  // ---- tiles 1..15 of this half (128 points each), 2-deep prefetch ----
  const float2* pp = (const float2*)(pb + (base0 + 128) * 3 + lane * 6);
  float2 A0 = pp[0], A1 = pp[1], A2 = pp[2];
  pp = (const float2*)(pb + (base0 + 256) * 3 + lane * 6);
  float2 B0 = pp[0], B1 = pp[1], B2 = pp[2];

#pragma unroll 1
  for (int it = 1; it < NPTS / 256; ++it) {
    const float2 c0 = A0, c1v = A1, c2 = A2;
    A0 = B0; A1 = B1; A2 = B2;
    if (it + 2 < NPTS / 256) {
      pp = (const float2*)(pb + (base0 + (it + 2) * 128) * 3 + lane * 6);
      B0 = pp[0]; B1 = pp[1]; B2 = pp[2];
    }
    float dx = qx - c0.x, dy = qy - c0.y, dz = qz - c1v.x;
    const float e2a = fmaf(dx, dx, fmaf(dy, dy, dz * dz));
    dx = qx - c1v.y; dy = qy - c2.x; dz = qz - c2.y;
    const float e2b = fmaf(dx, dx, fmaf(dy, dy, dz * dz));

    // batch compaction (rare): drain buffer via bitonic merges, tighten thr
    if (bcount >= BCT) {
#pragma unroll 1
      while (bcount > 0) {
        const int take = bcount < 40 ? bcount : 40;
        float mv = __builtin_inff();
        int mi = 0x7fffffff;
        if (lane < NSLOT) { mv = vald; mi = validx; }
        else if (lane - NSLOT < take) {
          mv = bdl[bcount - take + lane - NSLOT];
          mi = bil[bcount - take + lane - NSLOT];
        }
        BITONIC64(mv, mi)
        if (is_slot) { vald = mv; validx = mi; }
        bcount -= take;
      }
      const float v15 = __shfl(vald, 15);
      thr = v15 + v15 * 1e-5f;
    }

    KNN_EVENTS(e2a, base0 + it * 128, 0)
    KNN_EVENTS(e2b, base0 + it * 128, 1)
  }

  // ---- final drain ----
#pragma unroll 1
  while (bcount > 0) {
    const int take = bcount < 40 ? bcount : 40;
    float mv = __builtin_inff();
    int mi = 0x7fffffff;
    if (lane < NSLOT) { mv = vald; mi = validx; }
    else if (lane - NSLOT < take) {
      mv = bdl[bcount - take + lane - NSLOT];
      mi = bil[bcount - take + lane - NSLOT];
    }
    BITONIC64(mv, mi)
    if (is_slot) { vald = mv; validx = mi; }
    bcount -= take;
  }

  // ---- cross-wave merge: odd wave publishes its sorted 24 ----
  if (half == 1 && lane < NSLOT) { bdl[lane] = vald; bil[lane] = validx; }
  __syncthreads();
  if (half == 1) return;  // no further barriers below

  float mv = __builtin_inff();
  int mi = 0x7fffffff;
  if (lane < NSLOT) { mv = vald; mi = validx; }
  else if (lane < 2 * NSLOT) {
    mv = bd_s[w + 1][lane - NSLOT];
    mi = bi_s[w + 1][lane - NSLOT];
  }
  BITONIC64(mv, mi)  // merged: lanes 0..23 = global top-24

  // ---- exact f64 re-rank of the 24 survivors ----
  double d2e = 1e300;
  if (is_slot) {
    const double ex = (double)qx - (double)pb[mi * 3 + 0];
    const double ey = (double)qy - (double)pb[mi * 3 + 1];
    const double ez = (double)qz - (double)pb[mi * 3 + 2];
    d2e = ex * ex + ey * ey + ez * ez;
  }
  int rank = 0;
#pragma unroll 1
  for (int j = 0; j < NSLOT; ++j) {
    const double dj = __shfl(d2e, j);
    const int ij = __shfl(mi, j);
    if (dj < d2e || (dj == d2e && ij < mi)) ++rank;
  }
  if (is_slot && rank < KNN) knn_out[((b << 12) + qn) * KNN + rank] = mi;
}

// ---------------------------------------------------------------------------
// Fold body: Wqa = aw1@wq, Wka = aw1@wk, bf16 hi/lo split. (unchanged)
// ---------------------------------------------------------------------------
__device__ void fold_body(int bid, const float* __restrict__ aw1,
                          const float* __restrict__ wq, const float* __restrict__ wk,
                          short* __restrict__ WqaHi, short* __restrict__ WqaLo,
                          short* __restrict__ WkaHi, short* __restrict__ WkaLo) {
  const float* w = (bid < 64) ? wq : wk;
  short* oh = (bid < 64) ? WqaHi : WkaHi;
  short* ol = (bid < 64) ? WqaLo : WkaLo;
  const int row = ((bid & 63) << 1) + (threadIdx.x >> 7);
  const int i = threadIdx.x & 127;
  float acc = 0.f;
  for (int j = 0; j < 128; ++j) acc = fmaf(aw1[row * 128 + j], w[j * 128 + i], acc);
  const short h = f2b(acc);
  oh[row * 128 + i] = h;
  ol[row * 128 + i] = f2b(acc - b2f(h));
}

// ---------------------------------------------------------------------------
// M1 body (wave-parallel, coalesced). (unchanged)
// ---------------------------------------------------------------------------
__device__ void m1_body(int bid, const float* __restrict__ aw1,
                        const float* __restrict__ pw2, const float* __restrict__ pb2,
                        const float* __restrict__ ab1,
                        short* __restrict__ M1b, float* __restrict__ c1) {
  const int t = threadIdx.x;
  const int wid = t >> 6, lane = t & 63;
  const int o = bid * 4 + wid;
  const float a0 = aw1[o * 128 + lane];
  const float a1 = aw1[o * 128 + 64 + lane];

  float s = fmaf(a0, pb2[lane], a1 * pb2[64 + lane]);
#pragma unroll
  for (int off = 1; off < 64; off <<= 1) s += __shfl_xor(s, off);
  if (lane == 0) c1[o] = ab1[o] + s;

#pragma unroll
  for (int k = 0; k < HID; ++k) {
    float p = fmaf(a0, pw2[lane * HID + k], a1 * pw2[(64 + lane) * HID + k]);
#pragma unroll
    for (int off = 1; off < 64; off <<= 1) p += __shfl_xor(p, off);
    if (lane == 0) M1b[o * 32 + k] = f2b(p);
  }
  if (lane >= HID && lane < 32) M1b[o * 32 + lane] = 0;
}

__device__ void pw2b_body(const float* __restrict__ pw2, short* __restrict__ pw2b) {
  const int t = threadIdx.x;
  for (int i = t; i < 128 * 32; i += 256) {
    const int o = i >> 5, k = i & 31;
    pw2b[i] = (k < HID) ? f2b(pw2[o * HID + k]) : (short)0;
  }
}
__device__ void aw2b_body(int half, const float* __restrict__ aw2,
                          short* __restrict__ aw2b) {
  const int base = half * 8192;
  for (int i = threadIdx.x; i < 8192; i += 256) aw2b[base + i] = f2b(aw2[base + i]);
}
__device__ void wv_body(const float* __restrict__ wv, short* __restrict__ WvHi,
                        short* __restrict__ WvLo) {
  for (int i = threadIdx.x; i < 128 * 128; i += 256) {
    const float v = wv[i];
    const short h = f2b(v);
    WvHi[i] = h;
    WvLo[i] = f2b(v - b2f(h));
  }
}

// ---------------------------------------------------------------------------
// Launch 1: prep blocks FIRST, then knn (4096 blocks).
// ---------------------------------------------------------------------------
__global__ __launch_bounds__(256) void knn_prep_kernel(
    const float* __restrict__ pos, int* __restrict__ knn_out,
    const float* __restrict__ aw1, const float* __restrict__ wq,
    const float* __restrict__ wk,
    short* __restrict__ WqaHi, short* __restrict__ WqaLo,
    short* __restrict__ WkaHi, short* __restrict__ WkaLo,
    const float* __restrict__ pw2, const float* __restrict__ pb2,
    const float* __restrict__ ab1, const float* __restrict__ aw2,
    const float* __restrict__ wv,
    short* __restrict__ M1b, short* __restrict__ pw2b, short* __restrict__ aw2b,
    float* __restrict__ c1, short* __restrict__ WvHi, short* __restrict__ WvLo) {
  const int bid = blockIdx.x;
  if (bid < FOLD_BLOCKS) {
    fold_body(bid, aw1, wq, wk, WqaHi, WqaLo, WkaHi, WkaLo);
  } else if (bid < FOLD_BLOCKS + M1_BLOCKS) {
    m1_body(bid - FOLD_BLOCKS, aw1, pw2, pb2, ab1, M1b, c1);
  } else if (bid == FOLD_BLOCKS + M1_BLOCKS) {
    pw2b_body(pw2, pw2b);
  } else if (bid <= FOLD_BLOCKS + M1_BLOCKS + 2) {
    aw2b_body(bid - (FOLD_BLOCKS + M1_BLOCKS + 1), aw2, aw2b);
  } else if (bid == FOLD_BLOCKS + M1_BLOCKS + 3) {
    wv_body(wv, WvHi, WvLo);
  } else {
    knn_body(bid - PRE_BLOCKS, pos, knn_out);
  }
}

// ---------------------------------------------------------------------------
// Launch 2: MFMA projections with hi/lo bf16 compensation; bf16 outputs.
// ---------------------------------------------------------------------------
__global__ __launch_bounds__(256) void proj_mfma_kernel(
    const float* __restrict__ x,
    const short* __restrict__ WqaHi, const short* __restrict__ WqaLo,
    const short* __restrict__ WkaHi, const short* __restrict__ WkaLo,
    const short* __restrict__ WvHi, const short* __restrict__ WvLo,
    short* __restrict__ QAb, short* __restrict__ KAb, short* __restrict__ Vpb) {
  const int t = threadIdx.x;
  const int wid = t >> 6, lane = t & 63;
  const int r16 = lane & 15, g4 = lane >> 4;
  const int rowbase = blockIdx.x * 32 + (wid >> 1) * 16;
  const int ch = wid & 1;

  short8 ahi[4], alo[4];
#pragma unroll
  for (int ks = 0; ks < 4; ++ks) {
    const float* xp = x + (rowbase + r16) * DIM + ks * 32 + g4 * 8;
#pragma unroll
    for (int e = 0; e < 8; ++e) {
      const float v = xp[e];
      const short h = f2b(v);
      ahi[ks][e] = h;
      alo[ks][e] = f2b(v - b2f(h));
    }
  }

  const f32x4 zero4 = {0.f, 0.f, 0.f, 0.f};
  const short* WH[3] = {WqaHi, WkaHi, WvHi};
  const short* WL[3] = {WqaLo, WkaLo, WvLo};
  short* OUT[3] = {QAb, KAb, Vpb};
#pragma unroll
  for (int mi = 0; mi < 3; ++mi) {
    const short* wh = WH[mi];
    const short* wl = WL[mi];
    short* o = OUT[mi];
#pragma unroll
    for (int q = 0; q < 4; ++q) {
      const int col = (ch * 4 + q) * 16 + r16;
      f32x4 a = zero4;
#pragma unroll
      for (int ks = 0; ks < 4; ++ks) {
        const short8 bh = *(const short8*)(wh + col * DIM + ks * 32 + g4 * 8);
        const short8 bl = *(const short8*)(wl + col * DIM + ks * 32 + g4 * 8);
        a = __builtin_amdgcn_mfma_f32_16x16x32_bf16(ahi[ks], bh, a, 0, 0, 0);
        a = __builtin_amdgcn_mfma_f32_16x16x32_bf16(alo[ks], bh, a, 0, 0, 0);
        a = __builtin_amdgcn_mfma_f32_16x16x32_bf16(ahi[ks], bl, a, 0, 0, 0);
      }
#pragma unroll
      for (int reg = 0; reg < 4; ++reg)
        o[(rowbase + g4 * 4 + reg) * DIM + (ch * 4 + q) * 16 + r16] = f2b(a[reg]);
    }
  }
}

// ---------------------------------------------------------------------------
// Launch 3: main kernel — GRID-STRIDE over PTQ=4 queries per block
// (2048 blocks; same per-query code and register budget as r12; tests the
// block-churn/dispatch-ramp hypothesis). LDS reuse across iterations is
// barrier-ordered (3 barriers per iteration).
// ---------------------------------------------------------------------------
__global__ __launch_bounds__(256) void pt_wave_kernel(
    const float* __restrict__ pos, const int* __restrict__ knn_in,
    const short* __restrict__ QAb, const short* __restrict__ KAb,
    const short* __restrict__ Vpb,
    const float* __restrict__ pw1, const float* __restrict__ pb1,
    const float* __restrict__ pg, const float* __restrict__ pbeta,
    const float* __restrict__ pb2,
    const float* __restrict__ ag, const float* __restrict__ abeta,
    const float* __restrict__ ab2, const float* __restrict__ c1,
    const short* __restrict__ M1b, const short* __restrict__ pw2b,
    const short* __restrict__ aw2b,
    float* __restrict__ out) {
  __shared__ __align__(16) short z_s[2048];  // 16x128 bf16, XOR-swizzled
  __shared__ float red_s[2][4][16];          // [sum|sumsq][wave][row]
  __shared__ short hr_s[16][HID];            // pos_mlp output (bf16), per row

  const int t = threadIdx.x;
  const int wid = t >> 6;
  const int lane = t & 63;
  const int r16 = lane & 15;
  const int g4 = lane >> 4;
  const f32x4 zero4 = {0.f, 0.f, 0.f, 0.f};

#pragma unroll 1
  for (int qi = 0; qi < PTQ; ++qi) {
    const int n = blockIdx.x * PTQ + qi;  // flattened (b,n)
    const int b = n >> 12;

    // ---- phase 0: knn row (one 16-lane load), distribute via shfl ----
    int myidx = 0;
    if (lane < KNN) myidx = knn_in[n * KNN + lane];
    int jC[4];
#pragma unroll
    for (int reg = 0; reg < 4; ++reg) jC[reg] = __shfl(myidx, g4 * 4 + reg);

    const bool pm = (wid == 0) && (lane < 16);  // pos_mlp computing threads

    // ---- phase 1: issue ALL gathers up front ----
    float rx = 0.f, ry = 0.f, rz = 0.f;
    if (pm) {
      const int jg = b * NPTS + myidx;
      rx = pos[n * 3 + 0] - pos[jg * 3 + 0];
      ry = pos[n * 3 + 1] - pos[jg * 3 + 1];
      rz = pos[n * 3 + 2] - pos[jg * 3 + 2];
    }

    float qa_[2], kav[2][4], vv[2][4];
#pragma unroll
    for (int q = 0; q < 2; ++q) {
      const int o = (wid * 2 + q) * 16 + r16;
      qa_[q] = b2f(QAb[n * DIM + o]);
#pragma unroll
      for (int reg = 0; reg < 4; ++reg) {
        const int row = b * NPTS + jC[reg];
        kav[q][reg] = b2f(KAb[row * DIM + o]);
        vv[q][reg] = b2f(Vpb[row * DIM + o]);
      }
    }

    // ---- pos_mlp hidden + LN(12) + relu, ONCE (threads 0-15) ----
    if (pm) {
      float hr[HID];
      float mu = 0.f;
#pragma unroll
      for (int hh = 0; hh < HID; ++hh) {
        const float v = pb1[hh] + rx * pw1[hh * 3 + 0] + ry * pw1[hh * 3 + 1] +
                        rz * pw1[hh * 3 + 2];
        hr[hh] = v;
        mu += v;
      }
      mu *= (1.f / HID);
      float var = 0.f;
#pragma unroll
      for (int hh = 0; hh < HID; ++hh) { const float d = hr[hh] - mu; var = fmaf(d, d, var); }
      const float rsn = rsqrtf(var * (1.f / HID) + 1e-5f);
#pragma unroll
      for (int hh = 0; hh < HID; ++hh)
        hr_s[lane][hh] = f2b(fmaxf(fmaf((hr[hh] - mu) * rsn, pg[hh], pbeta[hh]), 0.f));
    }
    __syncthreads();  // B1

    // A1 fragment: A[r16][k], k=h (12, zero-padded to 32), from LDS broadcast
    short8 a1 = {0, 0, 0, 0, 0, 0, 0, 0};
    if (g4 == 0) {
#pragma unroll
      for (int e = 0; e < 8; ++e) a1[e] = hr_s[r16][e];
    } else if (g4 == 1) {
#pragma unroll
      for (int e = 0; e < 4; ++e) a1[e] = hr_s[r16][8 + e];
    }

    // MFMA1 over this wave's 2 col-tiles
    f32x4 accw[2], accp[2];
#pragma unroll
    for (int q = 0; q < 2; ++q) {
      const int boff = ((wid * 2 + q) * 16 + r16) * 32 + g4 * 8;
      const short8 bm = *(const short8*)(M1b + boff);
      const short8 bp = *(const short8*)(pw2b + boff);
      accw[q] = __builtin_amdgcn_mfma_f32_16x16x32_bf16(a1, bm, zero4, 0, 0, 0);
      accp[q] = __builtin_amdgcn_mfma_f32_16x16x32_bf16(a1, bp, zero4, 0, 0, 0);
    }

    // w1 = accw + QA - KA + c1
    float w1v[2][4];
#pragma unroll
    for (int q = 0; q < 2; ++q) {
      const int o = (wid * 2 + q) * 16 + r16;
      const float base = qa_[q] + c1[o];
#pragma unroll
      for (int reg = 0; reg < 4; ++reg)
        w1v[q][reg] = accw[q][reg] + base - kav[q][reg];
    }

    // LayerNorm row-stats: per-wave partial then cross-wave LDS reduce
    {
      float ps[4], pq2[4];
#pragma unroll
      for (int reg = 0; reg < 4; ++reg) {
        ps[reg] = w1v[0][reg] + w1v[1][reg];
        pq2[reg] = fmaf(w1v[0][reg], w1v[0][reg], w1v[1][reg] * w1v[1][reg]);
      }
#pragma unroll
      for (int reg = 0; reg < 4; ++reg) {
#pragma unroll
        for (int off = 1; off <= 8; off <<= 1) {
          ps[reg] += __shfl_xor(ps[reg], off);
          pq2[reg] += __shfl_xor(pq2[reg], off);
        }
      }
      if (r16 == 0) {
#pragma unroll
        for (int reg = 0; reg < 4; ++reg) {
          red_s[0][wid][g4 * 4 + reg] = ps[reg];
          red_s[1][wid][g4 * 4 + reg] = pq2[reg];
        }
      }
    }
    __syncthreads();  // B2
    float mu[4], rs[4];
#pragma unroll
    for (int reg = 0; reg < 4; ++reg) {
      const int rr = g4 * 4 + reg;
      const float s = red_s[0][0][rr] + red_s[0][1][rr] + red_s[0][2][rr] + red_s[0][3][rr];
      const float q2 = red_s[1][0][rr] + red_s[1][1][rr] + red_s[1][2][rr] + red_s[1][3][rr];
      mu[reg] = s * (1.f / 128.f);
      const float var = q2 * (1.f / 128.f) - mu[reg] * mu[reg];
      rs[reg] = rsqrtf(var + 1e-5f);
    }

    // gamma/relu, bf16-pack this wave's 32 cols into swizzled LDS
    {
      char* zb = (char*)z_s;
#pragma unroll
      for (int q = 0; q < 2; ++q) {
        const int o = (wid * 2 + q) * 16 + r16;
        const float gam = ag[o], bet = abeta[o];
#pragma unroll
        for (int reg = 0; reg < 4; ++reg) {
          const int rr = g4 * 4 + reg;
          const float zv = fmaxf(fmaf((w1v[q][reg] - mu[reg]) * rs[reg], gam, bet), 0.f);
          unsigned byte = (unsigned)(rr * 256 + o * 2);
          byte ^= ((unsigned)(rr & 7) << 4) ^ ((unsigned)(rr & 8) << 2);
          *(short*)(zb + byte) = f2b(zv);
        }
      }
    }
    __syncthreads();  // B3

    // A2 fragments: full 128-e range of rows r16
    short8 a2[4];
    {
      const char* zb = (const char*)z_s;
#pragma unroll
      for (int ks = 0; ks < 4; ++ks) {
        unsigned byte = (unsigned)(r16 * 256 + ks * 64 + g4 * 16);
        byte ^= ((unsigned)(r16 & 7) << 4) ^ ((unsigned)(r16 & 8) << 2);
        a2[ks] = *(const short8*)(zb + byte);
      }
    }

    // MFMA2 over this wave's 2 col-tiles (B from L1/L2-hot bf16 weights)
    f32x4 acc2[2] = {zero4, zero4};
#pragma unroll
    for (int q = 0; q < 2; ++q) {
#pragma unroll
      for (int ks = 0; ks < 4; ++ks) {
        const short8 bw =
            *(const short8*)(aw2b + ((wid * 2 + q) * 16 + r16) * DIM + ks * 32 + g4 * 8);
        acc2[q] = __builtin_amdgcn_mfma_f32_16x16x32_bf16(a2[ks], bw, acc2[q], 0, 0, 0);
      }
    }

    // softmax over k per column, weighted sum of (V + pe)
    float ew[2][4], inv[2];
#pragma unroll
    for (int q = 0; q < 2; ++q) {
      const float bb = ab2[(wid * 2 + q) * 16 + r16];
#pragma unroll
      for (int reg = 0; reg < 4; ++reg) ew[q][reg] = acc2[q][reg] + bb;
      float m = fmaxf(fmaxf(ew[q][0], ew[q][1]), fmaxf(ew[q][2], ew[q][3]));
      m = fmaxf(m, __shfl_xor(m, 16));
      m = fmaxf(m, __shfl_xor(m, 32));
      float s = 0.f;
#pragma unroll
      for (int reg = 0; reg < 4; ++reg) { ew[q][reg] = __expf(ew[q][reg] - m); s += ew[q][reg]; }
      s += __shfl_xor(s, 16);
      s += __shfl_xor(s, 32);
      inv[q] = 1.f / s;
    }

    float o_acc[2];
#pragma unroll
    for (int q = 0; q < 2; ++q) {
      const int o = (wid * 2 + q) * 16 + r16;
      const float pb = pb2[o];
      float acc = 0.f;
#pragma unroll
      for (int reg = 0; reg < 4; ++reg)
        acc = fmaf(ew[q][reg] * inv[q], vv[q][reg] + accp[q][reg] + pb, acc);
      acc += __shfl_xor(acc, 16);
      acc += __shfl_xor(acc, 32);
      o_acc[q] = acc;
    }
    if (g4 < 2) out[n * DIM + (wid * 2 + g4) * 16 + r16] = o_acc[g4];
  }
}

// ---------------------------------------------------------------------------
extern "C" void kernel_launch(void* const* d_in, const int* in_sizes, int n_in,
                              void* d_out, int out_size, void* d_ws, size_t ws_size,
                              hipStream_t stream) {
  const float* x   = (const float*)d_in[0];
  const float* pos = (const float*)d_in[1];
  const float* wq  = (const float*)d_in[2];
  const float* wk  = (const float*)d_in[3];
  const float* wv  = (const float*)d_in[4];
  const float* pw1 = (const float*)d_in[5];
  const float* pb1 = (const float*)d_in[6];
  const float* pg  = (const float*)d_in[7];
  const float* pbt = (const float*)d_in[8];
  const float* pw2 = (const float*)d_in[9];
  const float* pb2 = (const float*)d_in[10];
  const float* aw1 = (const float*)d_in[11];
  const float* ab1 = (const float*)d_in[12];
  const float* ag  = (const float*)d_in[13];
  const float* abt = (const float*)d_in[14];
  const float* aw2 = (const float*)d_in[15];
  const float* ab2 = (const float*)d_in[16];
  float* out = (float*)d_out;

  char* ws = (char*)d_ws;
  int*   knn   = (int*)ws;                          // 512 KB
  short* WqaHi = (short*)(ws + 512u * 1024u);       // 32 KB
  short* WqaLo = (short*)(ws + 544u * 1024u);       // 32 KB
  short* WkaHi = (short*)(ws + 576u * 1024u);       // 32 KB
  short* WkaLo = (short*)(ws + 608u * 1024u);       // 32 KB
  short* M1b   = (short*)(ws + 640u * 1024u);       // 8 KB
  short* pw2b  = (short*)(ws + 648u * 1024u);       // 8 KB
  short* aw2b  = (short*)(ws + 656u * 1024u);       // 32 KB
  float* c1    = (float*)(ws + 688u * 1024u);       // 512 B
  short* WvHi  = (short*)(ws + 704u * 1024u);       // 32 KB
  short* WvLo  = (short*)(ws + 736u * 1024u);       // 32 KB
  short* QAb   = (short*)(ws + (1u << 20));         // 2 MB
  short* KAb   = (short*)(ws + 4u * (1u << 20));    // 2 MB
  short* Vpb   = (short*)(ws + 7u * (1u << 20));    // 2 MB

  knn_prep_kernel<<<PRE_BLOCKS + KNN_BLOCKS, 256, 0, stream>>>(
      pos, knn, aw1, wq, wk, WqaHi, WqaLo, WkaHi, WkaLo, pw2, pb2, ab1, aw2, wv,
      M1b, pw2b, aw2b, c1, WvHi, WvLo);
  proj_mfma_kernel<<<BATCH * NPTS / 32, 256, 0, stream>>>(
      x, WqaHi, WqaLo, WkaHi, WkaLo, WvHi, WvLo, QAb, KAb, Vpb);
  pt_wave_kernel<<<BATCH * NPTS / PTQ, 256, 0, stream>>>(
      pos, knn, QAb, KAb, Vpb, pw1, pb1, pg, pbt, pb2, ag, abt, ab2, c1,
      M1b, pw2b, aw2b, out);
}

// Round 14
// 117.339 us; speedup vs baseline: 1.2105x; 1.2105x over previous
//
#include <hip/hip_runtime.h>
#include <hip/hip_bf16.h>
#include <math.h>

#define BATCH 2
#define NPTS 4096
#define DIM 128
#define HID 12
#define KNN 16
#define NSLOT 24   // sorted candidate list (top-24 by f32-lex, refined by f64)
#define BCAP 192   // append buffer capacity per wave
#define BCT 64     // compact threshold (checked before each 128-pt tile)
#define PTQ 4      // queries per pt_wave block (grid-stride)

// prep blocks first (stragglers start early), knn after
#define FOLD_BLOCKS 128
#define M1_BLOCKS 32
#define PRE_BLOCKS (FOLD_BLOCKS + M1_BLOCKS + 4)  // +pw2b +2*aw2b +wv = 164
#define KNN_BLOCKS (BATCH * NPTS / 4)             // 2048 (r12 one-wave-per-query)

typedef __attribute__((ext_vector_type(8))) short short8;
typedef __attribute__((ext_vector_type(4))) float f32x4;

// f32 -> bf16 round-to-nearest-even (finite values only)
__device__ __forceinline__ short f2b(float f) {
  unsigned u = __float_as_uint(f);
  unsigned r = (u + 0x7fffu + ((u >> 16) & 1u)) >> 16;
  return (short)r;
}
__device__ __forceinline__ float b2f(short h) {
  return __uint_as_float(((unsigned)(unsigned short)h) << 16);
}

// full-wave bitonic sort, ascending lexicographic by (value, index)
#define BITONIC64(v, vi)                                                     \
  {                                                                          \
    _Pragma("unroll") for (int k_ = 2; k_ <= 64; k_ <<= 1) {                 \
      _Pragma("unroll") for (int j_ = k_ >> 1; j_ >= 1; j_ >>= 1) {          \
        const float ov_ = __shfl_xor((v), j_);                               \
        const int oi_ = __shfl_xor((vi), j_);                                \
        const bool up_ = ((lane & k_) == 0);                                 \
        const bool lowpos_ = ((lane & j_) == 0);                             \
        const bool keep_min_ = (lowpos_ == up_);                             \
        const bool lt_ = (ov_ < (v)) || (ov_ == (v) && oi_ < (vi));          \
        const bool take_ = keep_min_ ? lt_ : !lt_;                           \
        if (take_) { (v) = ov_; (vi) = oi_; }                                \
      }                                                                      \
    }                                                                        \
  }

// ---------------------------------------------------------------------------
// KNN body: exact top-16 per query. ONE wave per query (r12 version — the
// 2-wave split of r13 regressed: looser thresholds + duplicated fixed cost).
// ---------------------------------------------------------------------------
__device__ void knn_body(int bid, const float* __restrict__ pos,
                         int* __restrict__ knn_out) {
  __shared__ float bd_s[4][BCAP];
  __shared__ int bi_s[4][BCAP];

  const int t = threadIdx.x;
  const int w = t >> 6;
  const int lane = t & 63;
  const int n = (bid << 2) + w;  // flattened (b,n), wave-uniform
  const int b = n >> 12;
  const int qn = n & (NPTS - 1);

  float* bdl = &bd_s[w][0];
  int* bil = &bi_s[w][0];

  const float* pb = pos + b * NPTS * 3;
  const float qx = pb[qn * 3 + 0];
  const float qy = pb[qn * 3 + 1];
  const float qz = pb[qn * 3 + 2];

  const bool is_slot = (lane < NSLOT);
  float vald, thr;
  int validx;
  int bcount = 0;

  // ---- tile 0 (points 0..127): seed via bitonic of even points ----
  {
    const float2* pp = (const float2*)(pb + lane * 6);
    const float2 u0 = pp[0], u1 = pp[1], u2 = pp[2];
    float dx = qx - u0.x, dy = qy - u0.y, dz = qz - u1.x;
    float v = fmaf(dx, dx, fmaf(dy, dy, dz * dz));
    int vi = lane * 2;
    dx = qx - u1.y; dy = qy - u2.x; dz = qz - u2.y;
    const float d2b = fmaf(dx, dx, fmaf(dy, dy, dz * dz));

    BITONIC64(v, vi)
    vald = is_slot ? v : __builtin_inff();
    validx = is_slot ? vi : 0x7fffffff;
    const float v15 = __shfl(v, 15);
    thr = v15 + v15 * 1e-5f;  // slack >> f32 rounding of d2

    const unsigned long long m = __ballot(d2b < thr);
    if (m) {
      const unsigned lt = __builtin_amdgcn_mbcnt_hi(
          (unsigned)(m >> 32), __builtin_amdgcn_mbcnt_lo((unsigned)m, 0u));
      if (d2b < thr) { bdl[lt] = d2b; bil[lt] = 2 * lane + 1; }
      bcount = (int)__builtin_popcountll(m);
    }
  }

  // ---- tiles 1..31 (128 points each), 2-deep prefetch ----
  const float2* pp = (const float2*)(pb + 384 + lane * 6);
  float2 A0 = pp[0], A1 = pp[1], A2 = pp[2];
  pp = (const float2*)(pb + 768 + lane * 6);
  float2 B0 = pp[0], B1 = pp[1], B2 = pp[2];

#pragma unroll 1
  for (int it = 1; it < NPTS / 128; ++it) {
    const float2 c0 = A0, c1v = A1, c2 = A2;
    A0 = B0; A1 = B1; A2 = B2;
    if (it + 2 < NPTS / 128) {
      pp = (const float2*)(pb + (it + 2) * 384 + lane * 6);
      B0 = pp[0]; B1 = pp[1]; B2 = pp[2];
    }
    float dx = qx - c0.x, dy = qy - c0.y, dz = qz - c1v.x;
    const float e2a = fmaf(dx, dx, fmaf(dy, dy, dz * dz));
    dx = qx - c1v.y; dy = qy - c2.x; dz = qz - c2.y;
    const float e2b = fmaf(dx, dx, fmaf(dy, dy, dz * dz));

    if (bcount >= BCT) {
#pragma unroll 1
      while (bcount > 0) {
        const int take = bcount < 40 ? bcount : 40;
        float mv = __builtin_inff();
        int mi = 0x7fffffff;
        if (lane < NSLOT) { mv = vald; mi = validx; }
        else if (lane - NSLOT < take) {
          mv = bdl[bcount - take + lane - NSLOT];
          mi = bil[bcount - take + lane - NSLOT];
        }
        BITONIC64(mv, mi)
        if (is_slot) { vald = mv; validx = mi; }
        bcount -= take;
      }
      const float v15 = __shfl(vald, 15);
      thr = v15 + v15 * 1e-5f;
    }

    {
      const unsigned long long m = __ballot(e2a < thr);
      if (m) {
        const unsigned lt = __builtin_amdgcn_mbcnt_hi(
            (unsigned)(m >> 32), __builtin_amdgcn_mbcnt_lo((unsigned)m, 0u));
        if (e2a < thr) { bdl[bcount + lt] = e2a; bil[bcount + lt] = it * 128 + 2 * lane; }
        bcount += (int)__builtin_popcountll(m);
      }
    }
    {
      const unsigned long long m = __ballot(e2b < thr);
      if (m) {
        const unsigned lt = __builtin_amdgcn_mbcnt_hi(
            (unsigned)(m >> 32), __builtin_amdgcn_mbcnt_lo((unsigned)m, 0u));
        if (e2b < thr) { bdl[bcount + lt] = e2b; bil[bcount + lt] = it * 128 + 2 * lane + 1; }
        bcount += (int)__builtin_popcountll(m);
      }
    }
  }

  // ---- final drain ----
#pragma unroll 1
  while (bcount > 0) {
    const int take = bcount < 40 ? bcount : 40;
    float mv = __builtin_inff();
    int mi = 0x7fffffff;
    if (lane < NSLOT) { mv = vald; mi = validx; }
    else if (lane - NSLOT < take) {
      mv = bdl[bcount - take + lane - NSLOT];
      mi = bil[bcount - take + lane - NSLOT];
    }
    BITONIC64(mv, mi)
    if (is_slot) { vald = mv; validx = mi; }
    bcount -= take;
  }

  // ---- exact f64 re-rank of the 24 survivors ----
  double d2e = 1e300;
  if (is_slot) {
    const double ex = (double)qx - (double)pb[validx * 3 + 0];
    const double ey = (double)qy - (double)pb[validx * 3 + 1];
    const double ez = (double)qz - (double)pb[validx * 3 + 2];
    d2e = ex * ex + ey * ey + ez * ez;
  }
  int rank = 0;
#pragma unroll 1
  for (int j = 0; j < NSLOT; ++j) {
    const double dj = __shfl(d2e, j);
    const int ij = __shfl(validx, j);
    if (dj < d2e || (dj == d2e && ij < validx)) ++rank;
  }
  if (is_slot && rank < KNN) knn_out[((b << 12) + qn) * KNN + rank] = validx;
}

// ---------------------------------------------------------------------------
// Fold body: Wqa = aw1@wq, Wka = aw1@wk, bf16 hi/lo split. (unchanged)
// ---------------------------------------------------------------------------
__device__ void fold_body(int bid, const float* __restrict__ aw1,
                          const float* __restrict__ wq, const float* __restrict__ wk,
                          short* __restrict__ WqaHi, short* __restrict__ WqaLo,
                          short* __restrict__ WkaHi, short* __restrict__ WkaLo) {
  const float* w = (bid < 64) ? wq : wk;
  short* oh = (bid < 64) ? WqaHi : WkaHi;
  short* ol = (bid < 64) ? WqaLo : WkaLo;
  const int row = ((bid & 63) << 1) + (threadIdx.x >> 7);
  const int i = threadIdx.x & 127;
  float acc = 0.f;
  for (int j = 0; j < 128; ++j) acc = fmaf(aw1[row * 128 + j], w[j * 128 + i], acc);
  const short h = f2b(acc);
  oh[row * 128 + i] = h;
  ol[row * 128 + i] = f2b(acc - b2f(h));
}

// ---------------------------------------------------------------------------
// M1 body (wave-parallel, coalesced). (unchanged)
// ---------------------------------------------------------------------------
__device__ void m1_body(int bid, const float* __restrict__ aw1,
                        const float* __restrict__ pw2, const float* __restrict__ pb2,
                        const float* __restrict__ ab1,
                        short* __restrict__ M1b, float* __restrict__ c1) {
  const int t = threadIdx.x;
  const int wid = t >> 6, lane = t & 63;
  const int o = bid * 4 + wid;
  const float a0 = aw1[o * 128 + lane];
  const float a1 = aw1[o * 128 + 64 + lane];

  float s = fmaf(a0, pb2[lane], a1 * pb2[64 + lane]);
#pragma unroll
  for (int off = 1; off < 64; off <<= 1) s += __shfl_xor(s, off);
  if (lane == 0) c1[o] = ab1[o] + s;

#pragma unroll
  for (int k = 0; k < HID; ++k) {
    float p = fmaf(a0, pw2[lane * HID + k], a1 * pw2[(64 + lane) * HID + k]);
#pragma unroll
    for (int off = 1; off < 64; off <<= 1) p += __shfl_xor(p, off);
    if (lane == 0) M1b[o * 32 + k] = f2b(p);
  }
  if (lane >= HID && lane < 32) M1b[o * 32 + lane] = 0;
}

__device__ void pw2b_body(const float* __restrict__ pw2, short* __restrict__ pw2b) {
  const int t = threadIdx.x;
  for (int i = t; i < 128 * 32; i += 256) {
    const int o = i >> 5, k = i & 31;
    pw2b[i] = (k < HID) ? f2b(pw2[o * HID + k]) : (short)0;
  }
}
__device__ void aw2b_body(int half, const float* __restrict__ aw2,
                          short* __restrict__ aw2b) {
  const int base = half * 8192;
  for (int i = threadIdx.x; i < 8192; i += 256) aw2b[base + i] = f2b(aw2[base + i]);
}
__device__ void wv_body(const float* __restrict__ wv, short* __restrict__ WvHi,
                        short* __restrict__ WvLo) {
  for (int i = threadIdx.x; i < 128 * 128; i += 256) {
    const float v = wv[i];
    const short h = f2b(v);
    WvHi[i] = h;
    WvLo[i] = f2b(v - b2f(h));
  }
}

// ---------------------------------------------------------------------------
// Launch 1: prep blocks FIRST, then knn (2048 blocks).
// ---------------------------------------------------------------------------
__global__ __launch_bounds__(256) void knn_prep_kernel(
    const float* __restrict__ pos, int* __restrict__ knn_out,
    const float* __restrict__ aw1, const float* __restrict__ wq,
    const float* __restrict__ wk,
    short* __restrict__ WqaHi, short* __restrict__ WqaLo,
    short* __restrict__ WkaHi, short* __restrict__ WkaLo,
    const float* __restrict__ pw2, const float* __restrict__ pb2,
    const float* __restrict__ ab1, const float* __restrict__ aw2,
    const float* __restrict__ wv,
    short* __restrict__ M1b, short* __restrict__ pw2b, short* __restrict__ aw2b,
    float* __restrict__ c1, short* __restrict__ WvHi, short* __restrict__ WvLo) {
  const int bid = blockIdx.x;
  if (bid < FOLD_BLOCKS) {
    fold_body(bid, aw1, wq, wk, WqaHi, WqaLo, WkaHi, WkaLo);
  } else if (bid < FOLD_BLOCKS + M1_BLOCKS) {
    m1_body(bid - FOLD_BLOCKS, aw1, pw2, pb2, ab1, M1b, c1);
  } else if (bid == FOLD_BLOCKS + M1_BLOCKS) {
    pw2b_body(pw2, pw2b);
  } else if (bid <= FOLD_BLOCKS + M1_BLOCKS + 2) {
    aw2b_body(bid - (FOLD_BLOCKS + M1_BLOCKS + 1), aw2, aw2b);
  } else if (bid == FOLD_BLOCKS + M1_BLOCKS + 3) {
    wv_body(wv, WvHi, WvLo);
  } else {
    knn_body(bid - PRE_BLOCKS, pos, knn_out);
  }
}

// ---------------------------------------------------------------------------
// Launch 2: MFMA projections with hi/lo bf16 compensation; bf16 outputs.
// ---------------------------------------------------------------------------
__global__ __launch_bounds__(256) void proj_mfma_kernel(
    const float* __restrict__ x,
    const short* __restrict__ WqaHi, const short* __restrict__ WqaLo,
    const short* __restrict__ WkaHi, const short* __restrict__ WkaLo,
    const short* __restrict__ WvHi, const short* __restrict__ WvLo,
    short* __restrict__ QAb, short* __restrict__ KAb, short* __restrict__ Vpb) {
  const int t = threadIdx.x;
  const int wid = t >> 6, lane = t & 63;
  const int r16 = lane & 15, g4 = lane >> 4;
  const int rowbase = blockIdx.x * 32 + (wid >> 1) * 16;
  const int ch = wid & 1;

  short8 ahi[4], alo[4];
#pragma unroll
  for (int ks = 0; ks < 4; ++ks) {
    const float* xp = x + (rowbase + r16) * DIM + ks * 32 + g4 * 8;
#pragma unroll
    for (int e = 0; e < 8; ++e) {
      const float v = xp[e];
      const short h = f2b(v);
      ahi[ks][e] = h;
      alo[ks][e] = f2b(v - b2f(h));
    }
  }

  const f32x4 zero4 = {0.f, 0.f, 0.f, 0.f};
  const short* WH[3] = {WqaHi, WkaHi, WvHi};
  const short* WL[3] = {WqaLo, WkaLo, WvLo};
  short* OUT[3] = {QAb, KAb, Vpb};
#pragma unroll
  for (int mi = 0; mi < 3; ++mi) {
    const short* wh = WH[mi];
    const short* wl = WL[mi];
    short* o = OUT[mi];
#pragma unroll
    for (int q = 0; q < 4; ++q) {
      const int col = (ch * 4 + q) * 16 + r16;
      f32x4 a = zero4;
#pragma unroll
      for (int ks = 0; ks < 4; ++ks) {
        const short8 bh = *(const short8*)(wh + col * DIM + ks * 32 + g4 * 8);
        const short8 bl = *(const short8*)(wl + col * DIM + ks * 32 + g4 * 8);
        a = __builtin_amdgcn_mfma_f32_16x16x32_bf16(ahi[ks], bh, a, 0, 0, 0);
        a = __builtin_amdgcn_mfma_f32_16x16x32_bf16(alo[ks], bh, a, 0, 0, 0);
        a = __builtin_amdgcn_mfma_f32_16x16x32_bf16(ahi[ks], bl, a, 0, 0, 0);
      }
#pragma unroll
      for (int reg = 0; reg < 4; ++reg)
        o[(rowbase + g4 * 4 + reg) * DIM + (ch * 4 + q) * 16 + r16] = f2b(a[reg]);
    }
  }
}

// ---------------------------------------------------------------------------
// Launch 3: main kernel — grid-stride PTQ=4 queries/block with ALL
// query-invariant MFMA B-fragments + epilogue scalars HOISTED to registers
// (deletes 12 address-divergent vector loads + 10 scalar loads per query
// per wave — the dominant TA-issue cost).
// ---------------------------------------------------------------------------
__global__ __launch_bounds__(256) void pt_wave_kernel(
    const float* __restrict__ pos, const int* __restrict__ knn_in,
    const short* __restrict__ QAb, const short* __restrict__ KAb,
    const short* __restrict__ Vpb,
    const float* __restrict__ pw1, const float* __restrict__ pb1,
    const float* __restrict__ pg, const float* __restrict__ pbeta,
    const float* __restrict__ pb2,
    const float* __restrict__ ag, const float* __restrict__ abeta,
    const float* __restrict__ ab2, const float* __restrict__ c1,
    const short* __restrict__ M1b, const short* __restrict__ pw2b,
    const short* __restrict__ aw2b,
    float* __restrict__ out) {
  __shared__ __align__(16) short z_s[2048];  // 16x128 bf16, XOR-swizzled
  __shared__ float red_s[2][4][16];          // [sum|sumsq][wave][row]
  __shared__ short hr_s[16][HID];            // pos_mlp output (bf16), per row

  const int t = threadIdx.x;
  const int wid = t >> 6;
  const int lane = t & 63;
  const int r16 = lane & 15;
  const int g4 = lane >> 4;
  const f32x4 zero4 = {0.f, 0.f, 0.f, 0.f};

  // ---- hoist query-invariant weights & scalars ----
  short8 BM[2], BP[2], BW[2][4];
  float c1v[2], agv[2], abtv[2], ab2v[2], pb2v[2];
#pragma unroll
  for (int q = 0; q < 2; ++q) {
    const int o = (wid * 2 + q) * 16 + r16;
    const int boff = o * 32 + g4 * 8;
    BM[q] = *(const short8*)(M1b + boff);
    BP[q] = *(const short8*)(pw2b + boff);
#pragma unroll
    for (int ks = 0; ks < 4; ++ks)
      BW[q][ks] = *(const short8*)(aw2b + o * DIM + ks * 32 + g4 * 8);
    c1v[q] = c1[o];
    agv[q] = ag[o];
    abtv[q] = abeta[o];
    ab2v[q] = ab2[o];
    pb2v[q] = pb2[o];
  }

#pragma unroll 1
  for (int qi = 0; qi < PTQ; ++qi) {
    const int n = blockIdx.x * PTQ + qi;  // flattened (b,n)
    const int b = n >> 12;

    // ---- knn row (one 16-lane load), distribute via shfl ----
    int myidx = 0;
    if (lane < KNN) myidx = knn_in[n * KNN + lane];
    int jC[4];
#pragma unroll
    for (int reg = 0; reg < 4; ++reg) jC[reg] = __shfl(myidx, g4 * 4 + reg);

    const bool pm = (wid == 0) && (lane < 16);  // pos_mlp computing threads

    // ---- issue gathers up front ----
    float rx = 0.f, ry = 0.f, rz = 0.f;
    if (pm) {
      const int jg = b * NPTS + myidx;
      rx = pos[n * 3 + 0] - pos[jg * 3 + 0];
      ry = pos[n * 3 + 1] - pos[jg * 3 + 1];
      rz = pos[n * 3 + 2] - pos[jg * 3 + 2];
    }

    float qa_[2], kav[2][4], vv[2][4];
#pragma unroll
    for (int q = 0; q < 2; ++q) {
      const int o = (wid * 2 + q) * 16 + r16;
      qa_[q] = b2f(QAb[n * DIM + o]);
#pragma unroll
      for (int reg = 0; reg < 4; ++reg) {
        const int row = b * NPTS + jC[reg];
        kav[q][reg] = b2f(KAb[row * DIM + o]);
        vv[q][reg] = b2f(Vpb[row * DIM + o]);
      }
    }

    // ---- pos_mlp hidden + LN(12) + relu, ONCE (threads 0-15) ----
    if (pm) {
      float hr[HID];
      float mu = 0.f;
#pragma unroll
      for (int hh = 0; hh < HID; ++hh) {
        const float v = pb1[hh] + rx * pw1[hh * 3 + 0] + ry * pw1[hh * 3 + 1] +
                        rz * pw1[hh * 3 + 2];
        hr[hh] = v;
        mu += v;
      }
      mu *= (1.f / HID);
      float var = 0.f;
#pragma unroll
      for (int hh = 0; hh < HID; ++hh) { const float d = hr[hh] - mu; var = fmaf(d, d, var); }
      const float rsn = rsqrtf(var * (1.f / HID) + 1e-5f);
#pragma unroll
      for (int hh = 0; hh < HID; ++hh)
        hr_s[lane][hh] = f2b(fmaxf(fmaf((hr[hh] - mu) * rsn, pg[hh], pbeta[hh]), 0.f));
    }
    __syncthreads();  // B1

    // A1 fragment from LDS broadcast
    short8 a1 = {0, 0, 0, 0, 0, 0, 0, 0};
    if (g4 == 0) {
#pragma unroll
      for (int e = 0; e < 8; ++e) a1[e] = hr_s[r16][e];
    } else if (g4 == 1) {
#pragma unroll
      for (int e = 0; e < 4; ++e) a1[e] = hr_s[r16][8 + e];
    }

    // MFMA1 (B-fragments from registers)
    f32x4 accw[2], accp[2];
#pragma unroll
    for (int q = 0; q < 2; ++q) {
      accw[q] = __builtin_amdgcn_mfma_f32_16x16x32_bf16(a1, BM[q], zero4, 0, 0, 0);
      accp[q] = __builtin_amdgcn_mfma_f32_16x16x32_bf16(a1, BP[q], zero4, 0, 0, 0);
    }

    // w1 = accw + QA - KA + c1
    float w1v[2][4];
#pragma unroll
    for (int q = 0; q < 2; ++q) {
      const float base = qa_[q] + c1v[q];
#pragma unroll
      for (int reg = 0; reg < 4; ++reg)
        w1v[q][reg] = accw[q][reg] + base - kav[q][reg];
    }

    // LayerNorm row-stats: per-wave partial then cross-wave LDS reduce
    {
      float ps[4], pq2[4];
#pragma unroll
      for (int reg = 0; reg < 4; ++reg) {
        ps[reg] = w1v[0][reg] + w1v[1][reg];
        pq2[reg] = fmaf(w1v[0][reg], w1v[0][reg], w1v[1][reg] * w1v[1][reg]);
      }
#pragma unroll
      for (int reg = 0; reg < 4; ++reg) {
#pragma unroll
        for (int off = 1; off <= 8; off <<= 1) {
          ps[reg] += __shfl_xor(ps[reg], off);
          pq2[reg] += __shfl_xor(pq2[reg], off);
        }
      }
      if (r16 == 0) {
#pragma unroll
        for (int reg = 0; reg < 4; ++reg) {
          red_s[0][wid][g4 * 4 + reg] = ps[reg];
          red_s[1][wid][g4 * 4 + reg] = pq2[reg];
        }
      }
    }
    __syncthreads();  // B2
    float mu[4], rs[4];
#pragma unroll
    for (int reg = 0; reg < 4; ++reg) {
      const int rr = g4 * 4 + reg;
      const float s = red_s[0][0][rr] + red_s[0][1][rr] + red_s[0][2][rr] + red_s[0][3][rr];
      const float q2 = red_s[1][0][rr] + red_s[1][1][rr] + red_s[1][2][rr] + red_s[1][3][rr];
      mu[reg] = s * (1.f / 128.f);
      const float var = q2 * (1.f / 128.f) - mu[reg] * mu[reg];
      rs[reg] = rsqrtf(var + 1e-5f);
    }

    // gamma/relu, bf16-pack this wave's 32 cols into swizzled LDS
    {
      char* zb = (char*)z_s;
#pragma unroll
      for (int q = 0; q < 2; ++q) {
        const int o = (wid * 2 + q) * 16 + r16;
#pragma unroll
        for (int reg = 0; reg < 4; ++reg) {
          const int rr = g4 * 4 + reg;
          const float zv = fmaxf(fmaf((w1v[q][reg] - mu[reg]) * rs[reg], agv[q], abtv[q]), 0.f);
          unsigned byte = (unsigned)(rr * 256 + o * 2);
          byte ^= ((unsigned)(rr & 7) << 4) ^ ((unsigned)(rr & 8) << 2);
          *(short*)(zb + byte) = f2b(zv);
        }
      }
    }
    __syncthreads();  // B3

    // A2 fragments
    short8 a2[4];
    {
      const char* zb = (const char*)z_s;
#pragma unroll
      for (int ks = 0; ks < 4; ++ks) {
        unsigned byte = (unsigned)(r16 * 256 + ks * 64 + g4 * 16);
        byte ^= ((unsigned)(r16 & 7) << 4) ^ ((unsigned)(r16 & 8) << 2);
        a2[ks] = *(const short8*)(zb + byte);
      }
    }

    // MFMA2 (B-fragments from registers)
    f32x4 acc2[2] = {zero4, zero4};
#pragma unroll
    for (int q = 0; q < 2; ++q) {
#pragma unroll
      for (int ks = 0; ks < 4; ++ks)
        acc2[q] = __builtin_amdgcn_mfma_f32_16x16x32_bf16(a2[ks], BW[q][ks], acc2[q], 0, 0, 0);
    }

    // softmax over k per column, weighted sum of (V + pe)
    float ew[2][4], inv[2];
#pragma unroll
    for (int q = 0; q < 2; ++q) {
#pragma unroll
      for (int reg = 0; reg < 4; ++reg) ew[q][reg] = acc2[q][reg] + ab2v[q];
      float m = fmaxf(fmaxf(ew[q][0], ew[q][1]), fmaxf(ew[q][2], ew[q][3]));
      m = fmaxf(m, __shfl_xor(m, 16));
      m = fmaxf(m, __shfl_xor(m, 32));
      float s = 0.f;
#pragma unroll
      for (int reg = 0; reg < 4; ++reg) { ew[q][reg] = __expf(ew[q][reg] - m); s += ew[q][reg]; }
      s += __shfl_xor(s, 16);
      s += __shfl_xor(s, 32);
      inv[q] = 1.f / s;
    }

    float o_acc[2];
#pragma unroll
    for (int q = 0; q < 2; ++q) {
      float acc = 0.f;
#pragma unroll
      for (int reg = 0; reg < 4; ++reg)
        acc = fmaf(ew[q][reg] * inv[q], vv[q][reg] + accp[q][reg] + pb2v[q], acc);
      acc += __shfl_xor(acc, 16);
      acc += __shfl_xor(acc, 32);
      o_acc[q] = acc;
    }
    if (g4 < 2) out[n * DIM + (wid * 2 + g4) * 16 + r16] = o_acc[g4];
  }
}

// ---------------------------------------------------------------------------
extern "C" void kernel_launch(void* const* d_in, const int* in_sizes, int n_in,
                              void* d_out, int out_size, void* d_ws, size_t ws_size,
                              hipStream_t stream) {
  const float* x   = (const float*)d_in[0];
  const float* pos = (const float*)d_in[1];
  const float* wq  = (const float*)d_in[2];
  const float* wk  = (const float*)d_in[3];
  const float* wv  = (const float*)d_in[4];
  const float* pw1 = (const float*)d_in[5];
  const float* pb1 = (const float*)d_in[6];
  const float* pg  = (const float*)d_in[7];
  const float* pbt = (const float*)d_in[8];
  const float* pw2 = (const float*)d_in[9];
  const float* pb2 = (const float*)d_in[10];
  const float* aw1 = (const float*)d_in[11];
  const float* ab1 = (const float*)d_in[12];
  const float* ag  = (const float*)d_in[13];
  const float* abt = (const float*)d_in[14];
  const float* aw2 = (const float*)d_in[15];
  const float* ab2 = (const float*)d_in[16];
  float* out = (float*)d_out;

  char* ws = (char*)d_ws;
  int*   knn   = (int*)ws;                          // 512 KB
  short* WqaHi = (short*)(ws + 512u * 1024u);       // 32 KB
  short* WqaLo = (short*)(ws + 544u * 1024u);       // 32 KB
  short* WkaHi = (short*)(ws + 576u * 1024u);       // 32 KB
  short* WkaLo = (short*)(ws + 608u * 1024u);       // 32 KB
  short* M1b   = (short*)(ws + 640u * 1024u);       // 8 KB
  short* pw2b  = (short*)(ws + 648u * 1024u);       // 8 KB
  short* aw2b  = (short*)(ws + 656u * 1024u);       // 32 KB
  float* c1    = (float*)(ws + 688u * 1024u);       // 512 B
  short* WvHi  = (short*)(ws + 704u * 1024u);       // 32 KB
  short* WvLo  = (short*)(ws + 736u * 1024u);       // 32 KB
  short* QAb   = (short*)(ws + (1u << 20));         // 2 MB
  short* KAb   = (short*)(ws + 4u * (1u << 20));    // 2 MB
  short* Vpb   = (short*)(ws + 7u * (1u << 20));    // 2 MB

  knn_prep_kernel<<<PRE_BLOCKS + KNN_BLOCKS, 256, 0, stream>>>(
      pos, knn, aw1, wq, wk, WqaHi, WqaLo, WkaHi, WkaLo, pw2, pb2, ab1, aw2, wv,
      M1b, pw2b, aw2b, c1, WvHi, WvLo);
  proj_mfma_kernel<<<BATCH * NPTS / 32, 256, 0, stream>>>(
      x, WqaHi, WqaLo, WkaHi, WkaLo, WvHi, WvLo, QAb, KAb, Vpb);
  pt_wave_kernel<<<BATCH * NPTS / PTQ, 256, 0, stream>>>(
      pos, knn, QAb, KAb, Vpb, pw1, pb1, pg, pbt, pb2, ag, abt, ab2, c1,
      M1b, pw2b, aw2b, out);
}